// Round 1
// 642.980 us; speedup vs baseline: 1.0371x; 1.0371x over previous
//
#include <hip/hip_runtime.h>
#include <stdint.h>

#define B_ROWS 32768
#define D_IN   512
#define D_OUT  2048
#define VBSZ   256
#define NVB    128   // B_ROWS / VBSZ
#define PROWS  512   // B_ROWS / 64: one partial-stats row per 64-row half-tile

typedef unsigned short u16;
typedef __bf16 bf16x8 __attribute__((ext_vector_type(8)));
typedef float  f32x4  __attribute__((ext_vector_type(4)));
typedef u16    u16x4  __attribute__((ext_vector_type(4)));
typedef u16    u16x8  __attribute__((ext_vector_type(8)));

__device__ __forceinline__ u16 f2bf(float f) {
  unsigned int u = __builtin_bit_cast(unsigned int, f);
  u += 0x7fffu + ((u >> 16) & 1u);  // RNE; finite inputs
  return (u16)(u >> 16);
}

// ---------------------------------------------------------------------------
// Kernel 0: fp32 -> bf16 pre-convert of A and W into workspace.
// ---------------------------------------------------------------------------
#define NA8 (B_ROWS * D_IN / 8)   // 2,097,152 groups of 8
#define NW8 (D_OUT * D_IN / 8)    //   131,072 groups of 8
__launch_bounds__(256)
__global__ void convert_kernel(const float* __restrict__ A, const float* __restrict__ W,
                               u16* __restrict__ Ab, u16* __restrict__ Wb) {
  const int idx = blockIdx.x * 256 + threadIdx.x;
  const float* src;
  u16* dst;
  if (idx < NA8)            { src = A + (size_t)idx * 8;         dst = Ab + (size_t)idx * 8; }
  else if (idx < NA8 + NW8) { src = W + (size_t)(idx - NA8) * 8; dst = Wb + (size_t)(idx - NA8) * 8; }
  else return;
  f32x4 a = *(const f32x4*)src, b = *(const f32x4*)(src + 4);
  u16x8 o;
  o[0]=f2bf(a[0]); o[1]=f2bf(a[1]); o[2]=f2bf(a[2]); o[3]=f2bf(a[3]);
  o[4]=f2bf(b[0]); o[5]=f2bf(b[1]); o[6]=f2bf(b[2]); o[7]=f2bf(b[3]);
  *(u16x8*)dst = o;
}

// ---------------------------------------------------------------------------
// Kernel 1: GEMM  X[m][n] = sum_k A[m][k] * W[n][k]  (bf16 in, fp32 out).
// m97 structure: 128x128 tile, BK=64, global_load_lds width-16 staging,
// 16x16x32 bf16 MFMA.
// DO_STATS epilogue: per-wave column sum / sum-of-squares over its 64-row
// half-tile (shfl_xor 16/32 folds the 4 lane-groups sharing a column),
// stored as exact-write partials colsum/colsq[bm*2+wm][col] — no atomics,
// no memset; eliminates the 268 MB stats re-read of X.
// ---------------------------------------------------------------------------
template <bool DO_STATS>
__launch_bounds__(256)
__global__ void gemm_bf16_kernel(const u16* __restrict__ A, const u16* __restrict__ Bw,
                                 float* __restrict__ X,
                                 float* __restrict__ colsum, float* __restrict__ colsq) {
  __shared__ __align__(16) u16 As[128 * 64];
  __shared__ __align__(16) u16 Bs[128 * 64];
  const int tid  = threadIdx.x;
  const int wave = tid >> 6;
  const int lane = tid & 63;
  const int bm = blockIdx.y, bn = blockIdx.x;
  const int wm = wave >> 1, wn = wave & 1;

  f32x4 acc[4][4] = {};

  // staging: thread t covers tile row (i*32 + t/8), k-cols (t%8)*8 .. +7
  const int r0 = tid >> 3;        // wave*8 + lane/8, 0..31
  const int c8 = (tid & 7) * 8;
  const u16* ga = A  + (size_t)(bm * 128 + r0) * D_IN + c8;
  const u16* gb = Bw + (size_t)(bn * 128 + r0) * D_IN + c8;
  u16* lA = &As[wave * 8 * 64];   // wave-uniform LDS bases
  u16* lB = &Bs[wave * 8 * 64];

  for (int kt = 0; kt < D_IN / 64; ++kt) {
    if (kt) __syncthreads();  // prev tile's LDS reads complete before overwrite
#pragma unroll
    for (int i = 0; i < 4; ++i) {
      __builtin_amdgcn_global_load_lds(
          (const __attribute__((address_space(1))) void*)(ga + (size_t)i * 32 * D_IN + kt * 64),
          (__attribute__((address_space(3))) void*)(lA + i * 32 * 64), 16, 0, 0);
      __builtin_amdgcn_global_load_lds(
          (const __attribute__((address_space(1))) void*)(gb + (size_t)i * 32 * D_IN + kt * 64),
          (__attribute__((address_space(3))) void*)(lB + i * 32 * 64), 16, 0, 0);
    }
    __builtin_amdgcn_s_waitcnt(0x0f70);  // vmcnt(0)
    __syncthreads();

#pragma unroll
    for (int kk = 0; kk < 2; ++kk) {
      const int kc = kk * 32 + ((lane >> 4) << 3);  // frag: k = quad*8 + j
      bf16x8 af[4], bg[4];
#pragma unroll
      for (int i = 0; i < 4; ++i) {
        const int ar = wm * 64 + i * 16 + (lane & 15);
        af[i] = __builtin_bit_cast(bf16x8, *(const u16x8*)(&As[ar * 64 + kc]));
        const int br = wn * 64 + i * 16 + (lane & 15);
        bg[i] = __builtin_bit_cast(bf16x8, *(const u16x8*)(&Bs[br * 64 + kc]));
      }
#pragma unroll
      for (int i = 0; i < 4; ++i)
#pragma unroll
        for (int j = 0; j < 4; ++j)
          acc[i][j] = __builtin_amdgcn_mfma_f32_16x16x32_bf16(af[i], bg[j], acc[i][j], 0, 0, 0);
    }
  }

  // C/D layout: col = lane&15, row = (lane>>4)*4 + reg  [m89/m91]
#pragma unroll
  for (int i = 0; i < 4; ++i) {
    const int rr = bm * 128 + wm * 64 + i * 16 + ((lane >> 4) << 2);
#pragma unroll
    for (int j = 0; j < 4; ++j) {
      const int c = bn * 128 + wn * 64 + j * 16 + (lane & 15);
#pragma unroll
      for (int r = 0; r < 4; ++r)
        X[(size_t)(rr + r) * D_OUT + c] = acc[i][j][r];
    }
  }

  if constexpr (DO_STATS) {
    // This wave's (wm, wn) owns a 64-row x 64-col sub-tile. For column
    // (wn*64 + j*16 + lane&15): thread holds 16 of its 64 rows (i, reg).
    // shfl_xor 16/32 folds lanes {l, l^16, l^32, l^48} (same lane&15) ->
    // full 64-row column sum; lanes 0..15 store the partial.
#pragma unroll
    for (int j = 0; j < 4; ++j) {
      float s = 0.f, q = 0.f;
#pragma unroll
      for (int i = 0; i < 4; ++i)
#pragma unroll
        for (int r = 0; r < 4; ++r) { const float v = acc[i][j][r]; s += v; q += v * v; }
      s += __shfl_xor(s, 16, 64); s += __shfl_xor(s, 32, 64);
      q += __shfl_xor(q, 16, 64); q += __shfl_xor(q, 32, 64);
      if (lane < 16) {
        const int col = bn * 128 + wn * 64 + j * 16 + lane;
        const size_t p = (size_t)(bm * 2 + wm) * D_OUT + col;  // rows bm*128+wm*64 .. +63
        colsum[p] = s;
        colsq[p]  = q;
      }
    }
  }
}

// Fallback GEMM (ws too small for bf16 copies): fp32 loads, in-register bf16
// conversion, reg->LDS staging (round-3 verified path).
__launch_bounds__(256)
__global__ void gemm_f32stage_kernel(const float* __restrict__ A, const float* __restrict__ Bw,
                                     float* __restrict__ X) {
  __shared__ __align__(16) u16 As[128 * 64];
  __shared__ __align__(16) u16 Bs[128 * 64];
  const int tid  = threadIdx.x;
  const int wave = tid >> 6;
  const int lane = tid & 63;
  const int bm = blockIdx.y, bn = blockIdx.x;
  const int wm = wave >> 1, wn = wave & 1;
  f32x4 acc[4][4] = {};
  const int r0 = tid >> 3;
  const int c8 = (tid & 7) * 8;
  const float* ga = A  + (size_t)(bm * 128 + r0) * D_IN + c8;
  const float* gb = Bw + (size_t)(bn * 128 + r0) * D_IN + c8;

  for (int kt = 0; kt < D_IN / 64; ++kt) {
    u16x8 av[4], bv[4];
#pragma unroll
    for (int i = 0; i < 4; ++i) {
      const float* pa = ga + (size_t)i * 32 * D_IN + kt * 64;
      const float* pb = gb + (size_t)i * 32 * D_IN + kt * 64;
      f32x4 a0 = *(const f32x4*)pa, a1 = *(const f32x4*)(pa + 4);
      f32x4 b0 = *(const f32x4*)pb, b1 = *(const f32x4*)(pb + 4);
#pragma unroll
      for (int q = 0; q < 4; ++q) {
        av[i][q] = f2bf(a0[q]); av[i][q + 4] = f2bf(a1[q]);
        bv[i][q] = f2bf(b0[q]); bv[i][q + 4] = f2bf(b1[q]);
      }
    }
    if (kt) __syncthreads();
#pragma unroll
    for (int i = 0; i < 4; ++i) {
      *(u16x8*)&As[(i * 32 + r0) * 64 + c8] = av[i];
      *(u16x8*)&Bs[(i * 32 + r0) * 64 + c8] = bv[i];
    }
    __syncthreads();
#pragma unroll
    for (int kk = 0; kk < 2; ++kk) {
      const int kc = kk * 32 + ((lane >> 4) << 3);
      bf16x8 af[4], bg[4];
#pragma unroll
      for (int i = 0; i < 4; ++i) {
        af[i] = __builtin_bit_cast(bf16x8, *(const u16x8*)(&As[(wm * 64 + i * 16 + (lane & 15)) * 64 + kc]));
        bg[i] = __builtin_bit_cast(bf16x8, *(const u16x8*)(&Bs[(wn * 64 + i * 16 + (lane & 15)) * 64 + kc]));
      }
#pragma unroll
      for (int i = 0; i < 4; ++i)
#pragma unroll
        for (int j = 0; j < 4; ++j)
          acc[i][j] = __builtin_amdgcn_mfma_f32_16x16x32_bf16(af[i], bg[j], acc[i][j], 0, 0, 0);
    }
  }
#pragma unroll
  for (int i = 0; i < 4; ++i) {
    const int rr = bm * 128 + wm * 64 + i * 16 + ((lane >> 4) << 2);
#pragma unroll
    for (int j = 0; j < 4; ++j) {
      const int c = bn * 128 + wn * 64 + j * 16 + (lane & 15);
#pragma unroll
      for (int r = 0; r < 4; ++r)
        X[(size_t)(rr + r) * D_OUT + c] = acc[i][j][r];
    }
  }
}

// ---------------------------------------------------------------------------
// Kernel 2a: finalize stats from GEMM partials. vb combines partials
// p = 4*vb .. 4*vb+3 (each a 64-row half-tile). Reads 8 MB, writes 2 MB.
// ---------------------------------------------------------------------------
__launch_bounds__(256)
__global__ void finalize_stats_kernel(const float* __restrict__ colsum,
                                      const float* __restrict__ colsq,
                                      float* __restrict__ mean, float* __restrict__ istd) {
  const int idx = blockIdx.x * 256 + threadIdx.x;   // vb*D_OUT + c, 262144 total
  const int vb = idx >> 11;
  const int c  = idx & (D_OUT - 1);
  float s = 0.f, q = 0.f;
#pragma unroll
  for (int p = 0; p < 4; ++p) {
    const size_t o = (size_t)(vb * 4 + p) * D_OUT + c;
    s += colsum[o]; q += colsq[o];
  }
  const float m = s * (1.0f / VBSZ);
  mean[idx] = m;
  istd[idx] = rsqrtf(q * (1.0f / VBSZ) - m * m + 1e-5f);  // biased var, BN training
}

// ---------------------------------------------------------------------------
// Kernel 2b (fallback only): per-(virtual batch, column) mean & inv-std.
// ---------------------------------------------------------------------------
__launch_bounds__(256)
__global__ void stats_kernel(const float* __restrict__ X, float* __restrict__ mean,
                             float* __restrict__ istd) {
  const int vb = blockIdx.y;
  const int c  = blockIdx.x * 256 + threadIdx.x;
  const float* p = X + (size_t)vb * VBSZ * D_OUT + c;
  float s = 0.f, q = 0.f;
#pragma unroll 8
  for (int r = 0; r < VBSZ; ++r) {
    const float v = p[(size_t)r * D_OUT];
    s += v; q += v * v;
  }
  const float m = s * (1.0f / VBSZ);
  const size_t o = (size_t)vb * D_OUT + c;
  mean[o] = m;
  istd[o] = rsqrtf(q * (1.0f / VBSZ) - m * m + 1e-5f);
}

// ---------------------------------------------------------------------------
// Kernel 3: BN apply + prior scale + sparsemax. One wave per row; z in 32
// regs. Michelot's algorithm entirely in registers (no LDS): thr_0 = max-1
// (provably <= tau*, so S_0 contains the support); iterate
// tau = (sum_{z>thr} z - 1)/|{z>thr}|, thr <- tau; support shrinks
// monotonically, terminate when |S| unchanged (tau then exact). Typically
// 3-5 iterations of ~32 predicated reg ops + one butterfly — replaces the
// 24-iteration LDS binary search (serial ~120cy LDS latency chain) and the
// 32 KB cand buffer (occupancy 5 -> 8 blocks/CU). In-place.
// ---------------------------------------------------------------------------
__launch_bounds__(256)
__global__ void sparsemax_kernel(const float* __restrict__ X, const float* __restrict__ priors,
                                 const float* __restrict__ gamma, const float* __restrict__ beta,
                                 const float* __restrict__ mean, const float* __restrict__ istd,
                                 float* __restrict__ out) {
  const int wave = threadIdx.x >> 6;
  const int lane = threadIdx.x & 63;
  const int row  = blockIdx.x * 4 + wave;
  const int vb   = row >> 8;
  const size_t rowoff = (size_t)row * D_OUT;

  float z[32];
  float mx = -1e30f;
#pragma unroll
  for (int j = 0; j < 8; ++j) {
    const int c = j * 256 + lane * 4;
    f32x4 xv = *(const f32x4*)(X + rowoff + c);
    f32x4 mu = *(const f32x4*)(mean + (size_t)vb * D_OUT + c);
    f32x4 is = *(const f32x4*)(istd + (size_t)vb * D_OUT + c);
    f32x4 g  = *(const f32x4*)(gamma + c);
    f32x4 be = *(const f32x4*)(beta + c);
    f32x4 pr = *(const f32x4*)(priors + rowoff + c);
#pragma unroll
    for (int q = 0; q < 4; ++q) {
      const float zz = ((xv[q] - mu[q]) * is[q] * g[q] + be[q]) * pr[q];
      z[j * 4 + q] = zz;
      mx = fmaxf(mx, zz);
    }
  }
#pragma unroll
  for (int m = 32; m; m >>= 1) mx = fmaxf(mx, __shfl_xor(mx, m, 64));

  // Michelot: f(mx-1) >= 1 => tau* >= mx-1, so S_0 = {z > mx-1} covers the
  // support; tau_t monotonically increases toward tau*, S_t shrinks.
  float thr = mx - 1.0f;
  float kprev = -1.0f;
  float tau;
  for (;;) {
    float s = 0.f, k = 0.f;
#pragma unroll
    for (int j = 0; j < 32; ++j) {
      if (z[j] > thr) { s += z[j]; k += 1.f; }
    }
#pragma unroll
    for (int m = 32; m; m >>= 1) { s += __shfl_xor(s, m, 64); k += __shfl_xor(k, m, 64); }
    tau = (s - 1.0f) / k;
    if (k == kprev) break;   // support stable -> tau exact; wave-uniform
    kprev = k;
    thr = tau;
  }

#pragma unroll
  for (int j = 0; j < 8; ++j) {
    const int c = j * 256 + lane * 4;
    f32x4 o;
#pragma unroll
    for (int q = 0; q < 4; ++q) o[q] = fmaxf(z[j * 4 + q] - tau, 0.f);
    *(f32x4*)(out + rowoff + c) = o;
  }
}

// ---------------------------------------------------------------------------
// ws layout (main): [A_bf16 33.5MB][W_bf16 2MB][colsum 4MB][colsq 4MB]
//                   [mean 1MB][istd 1MB] = 45.5 MB.
// Middle path (ws >= 37.5MB): bf16 GEMM without stats epilogue + stats pass.
// Fallback (ws >= 2MB): fp32-staging GEMM + stats pass.
// d_out (fp32, 268MB) doubles as the X intermediate.
// ---------------------------------------------------------------------------
extern "C" void kernel_launch(void* const* d_in, const int* in_sizes, int n_in,
                              void* d_out, int out_size, void* d_ws, size_t ws_size,
                              hipStream_t stream) {
  const float* priors = (const float*)d_in[0];
  const float* feat   = (const float*)d_in[1];
  const float* Wt     = (const float*)d_in[2];
  const float* gamma  = (const float*)d_in[3];
  const float* beta   = (const float*)d_in[4];
  float* X = (float*)d_out;

  const size_t a_bytes  = (size_t)B_ROWS * D_IN * sizeof(u16);   // 33.5 MB
  const size_t w_bytes  = (size_t)D_OUT * D_IN * sizeof(u16);    //  2  MB
  const size_t st_elems = (size_t)NVB * D_OUT;                   // 262144
  const size_t pt_elems = (size_t)PROWS * D_OUT;                 // 1048576

  const dim3 ggrid(D_OUT / 128, B_ROWS / 128);
  const int  stats_fin_blocks = (int)(st_elems / 256);           // 1024

  if (ws_size >= a_bytes + w_bytes + (2 * pt_elems + 2 * st_elems) * sizeof(float)) {
    // Main: fused-stats GEMM, no 268 MB stats re-read.
    u16* Ab = (u16*)d_ws;
    u16* Wb = (u16*)((char*)d_ws + a_bytes);
    float* colsum = (float*)((char*)d_ws + a_bytes + w_bytes);
    float* colsq  = colsum + pt_elems;
    float* mean   = colsq + pt_elems;
    float* istd   = mean + st_elems;
    convert_kernel<<<(NA8 + NW8) / 256, 256, 0, stream>>>(feat, Wt, Ab, Wb);
    gemm_bf16_kernel<true><<<ggrid, 256, 0, stream>>>(Ab, Wb, X, colsum, colsq);
    finalize_stats_kernel<<<stats_fin_blocks, 256, 0, stream>>>(colsum, colsq, mean, istd);
    sparsemax_kernel<<<B_ROWS / 4, 256, 0, stream>>>(X, priors, gamma, beta, mean, istd, X);
  } else if (ws_size >= a_bytes + w_bytes + 2 * st_elems * sizeof(float)) {
    // Middle: bf16 GEMM (no epilogue) + separate stats pass.
    u16* Ab = (u16*)d_ws;
    u16* Wb = (u16*)((char*)d_ws + a_bytes);
    float* mean = (float*)((char*)d_ws + a_bytes + w_bytes);
    float* istd = mean + st_elems;
    convert_kernel<<<(NA8 + NW8) / 256, 256, 0, stream>>>(feat, Wt, Ab, Wb);
    gemm_bf16_kernel<false><<<ggrid, 256, 0, stream>>>(Ab, Wb, X, nullptr, nullptr);
    stats_kernel<<<dim3(8, NVB), 256, 0, stream>>>(X, mean, istd);
    sparsemax_kernel<<<B_ROWS / 4, 256, 0, stream>>>(X, priors, gamma, beta, mean, istd, X);
  } else {
    float* mean = (float*)d_ws;
    float* istd = mean + st_elems;
    gemm_f32stage_kernel<<<ggrid, 256, 0, stream>>>(feat, Wt, X);
    stats_kernel<<<dim3(8, NVB), 256, 0, stream>>>(X, mean, istd);
    sparsemax_kernel<<<B_ROWS / 4, 256, 0, stream>>>(X, priors, gamma, beta, mean, istd, X);
  }
}

// Round 2
// 574.535 us; speedup vs baseline: 1.1607x; 1.1191x over previous
//
#include <hip/hip_runtime.h>
#include <stdint.h>

#define B_ROWS 32768
#define D_IN   512
#define D_OUT  2048
#define VBSZ   256
#define NVB    128   // B_ROWS / VBSZ
#define PROWS  512   // B_ROWS / 64: one partial-stats row per 64-row half-tile
#define XSLOT  4096  // u16 elements per d_out row slot (8 KB); X-f16 row r at slot r, offset +2048

typedef unsigned short u16;
typedef __bf16 bf16x8 __attribute__((ext_vector_type(8)));
typedef float  f32x4  __attribute__((ext_vector_type(4)));
typedef u16    u16x4  __attribute__((ext_vector_type(4)));
typedef u16    u16x8  __attribute__((ext_vector_type(8)));
typedef _Float16 h16x4 __attribute__((ext_vector_type(4)));

__device__ __forceinline__ u16 f2bf(float f) {
  unsigned int u = __builtin_bit_cast(unsigned int, f);
  u += 0x7fffu + ((u >> 16) & 1u);  // RNE; finite inputs
  return (u16)(u >> 16);
}
__device__ __forceinline__ u16 f2h(float f) {
  return __builtin_bit_cast(u16, (_Float16)f);  // v_cvt_f16_f32, RNE
}

// ---------------------------------------------------------------------------
// Kernel 0: fp32 -> bf16 pre-convert of A and W into workspace.
// ---------------------------------------------------------------------------
#define NA8 (B_ROWS * D_IN / 8)   // 2,097,152 groups of 8
#define NW8 (D_OUT * D_IN / 8)    //   131,072 groups of 8
__launch_bounds__(256)
__global__ void convert_kernel(const float* __restrict__ A, const float* __restrict__ W,
                               u16* __restrict__ Ab, u16* __restrict__ Wb) {
  const int idx = blockIdx.x * 256 + threadIdx.x;
  const float* src;
  u16* dst;
  if (idx < NA8)            { src = A + (size_t)idx * 8;         dst = Ab + (size_t)idx * 8; }
  else if (idx < NA8 + NW8) { src = W + (size_t)(idx - NA8) * 8; dst = Wb + (size_t)(idx - NA8) * 8; }
  else return;
  f32x4 a = *(const f32x4*)src, b = *(const f32x4*)(src + 4);
  u16x8 o;
  o[0]=f2bf(a[0]); o[1]=f2bf(a[1]); o[2]=f2bf(a[2]); o[3]=f2bf(a[3]);
  o[4]=f2bf(b[0]); o[5]=f2bf(b[1]); o[6]=f2bf(b[2]); o[7]=f2bf(b[3]);
  *(u16x8*)dst = o;
}

// ---------------------------------------------------------------------------
// Kernel 1: GEMM  X[m][n] = sum_k A[m][k] * W[n][k]  (bf16 in).
// m97 structure: 128x128 tile, BK=64, global_load_lds width-16 staging,
// 16x16x32 bf16 MFMA.
// X is written as fp16 into the upper 4 KB of each d_out 8 KB row slot
// (halves write traffic; 134 MB of X lines fit the 256 MB L3 for the
// sparsemax re-read; sparsemax block r is sole reader+writer of slot r).
// Stats are computed from the fp32 accumulators (f16 never touches stats).
// DO_STATS epilogue: per-wave column sum / sum-of-squares over its 64-row
// half-tile (shfl_xor 16/32 folds the 4 lane-groups sharing a column),
// stored as exact-write partials colsum/colsq[bm*2+wm][col].
// ---------------------------------------------------------------------------
template <bool DO_STATS>
__launch_bounds__(256)
__global__ void gemm_bf16_kernel(const u16* __restrict__ A, const u16* __restrict__ Bw,
                                 u16* __restrict__ Xh,
                                 float* __restrict__ colsum, float* __restrict__ colsq) {
  __shared__ __align__(16) u16 As[128 * 64];
  __shared__ __align__(16) u16 Bs[128 * 64];
  const int tid  = threadIdx.x;
  const int wave = tid >> 6;
  const int lane = tid & 63;
  const int bm = blockIdx.y, bn = blockIdx.x;
  const int wm = wave >> 1, wn = wave & 1;

  f32x4 acc[4][4] = {};

  // staging: thread t covers tile row (i*32 + t/8), k-cols (t%8)*8 .. +7
  const int r0 = tid >> 3;        // wave*8 + lane/8, 0..31
  const int c8 = (tid & 7) * 8;
  const u16* ga = A  + (size_t)(bm * 128 + r0) * D_IN + c8;
  const u16* gb = Bw + (size_t)(bn * 128 + r0) * D_IN + c8;
  u16* lA = &As[wave * 8 * 64];   // wave-uniform LDS bases
  u16* lB = &Bs[wave * 8 * 64];

  for (int kt = 0; kt < D_IN / 64; ++kt) {
    if (kt) __syncthreads();  // prev tile's LDS reads complete before overwrite
#pragma unroll
    for (int i = 0; i < 4; ++i) {
      __builtin_amdgcn_global_load_lds(
          (const __attribute__((address_space(1))) void*)(ga + (size_t)i * 32 * D_IN + kt * 64),
          (__attribute__((address_space(3))) void*)(lA + i * 32 * 64), 16, 0, 0);
      __builtin_amdgcn_global_load_lds(
          (const __attribute__((address_space(1))) void*)(gb + (size_t)i * 32 * D_IN + kt * 64),
          (__attribute__((address_space(3))) void*)(lB + i * 32 * 64), 16, 0, 0);
    }
    __builtin_amdgcn_s_waitcnt(0x0f70);  // vmcnt(0)
    __syncthreads();

#pragma unroll
    for (int kk = 0; kk < 2; ++kk) {
      const int kc = kk * 32 + ((lane >> 4) << 3);  // frag: k = quad*8 + j
      bf16x8 af[4], bg[4];
#pragma unroll
      for (int i = 0; i < 4; ++i) {
        const int ar = wm * 64 + i * 16 + (lane & 15);
        af[i] = __builtin_bit_cast(bf16x8, *(const u16x8*)(&As[ar * 64 + kc]));
        const int br = wn * 64 + i * 16 + (lane & 15);
        bg[i] = __builtin_bit_cast(bf16x8, *(const u16x8*)(&Bs[br * 64 + kc]));
      }
#pragma unroll
      for (int i = 0; i < 4; ++i)
#pragma unroll
        for (int j = 0; j < 4; ++j)
          acc[i][j] = __builtin_amdgcn_mfma_f32_16x16x32_bf16(af[i], bg[j], acc[i][j], 0, 0, 0);
    }
  }

  // C/D layout: col = lane&15, row = (lane>>4)*4 + reg  [m89/m91]
#pragma unroll
  for (int i = 0; i < 4; ++i) {
    const int rr = bm * 128 + wm * 64 + i * 16 + ((lane >> 4) << 2);
#pragma unroll
    for (int j = 0; j < 4; ++j) {
      const int c = bn * 128 + wn * 64 + j * 16 + (lane & 15);
#pragma unroll
      for (int r = 0; r < 4; ++r)
        Xh[(size_t)(rr + r) * XSLOT + 2048 + c] = f2h(acc[i][j][r]);
    }
  }

  if constexpr (DO_STATS) {
    // This wave's (wm, wn) owns a 64-row x 64-col sub-tile. For column
    // (wn*64 + j*16 + lane&15): thread holds 16 of its 64 rows (i, reg).
    // shfl_xor 16/32 folds lanes {l, l^16, l^32, l^48} (same lane&15) ->
    // full 64-row column sum; lanes 0..15 store the partial.
#pragma unroll
    for (int j = 0; j < 4; ++j) {
      float s = 0.f, q = 0.f;
#pragma unroll
      for (int i = 0; i < 4; ++i)
#pragma unroll
        for (int r = 0; r < 4; ++r) { const float v = acc[i][j][r]; s += v; q += v * v; }
      s += __shfl_xor(s, 16, 64); s += __shfl_xor(s, 32, 64);
      q += __shfl_xor(q, 16, 64); q += __shfl_xor(q, 32, 64);
      if (lane < 16) {
        const int col = bn * 128 + wn * 64 + j * 16 + lane;
        const size_t p = (size_t)(bm * 2 + wm) * D_OUT + col;  // rows bm*128+wm*64 .. +63
        colsum[p] = s;
        colsq[p]  = q;
      }
    }
  }
}

// Fallback GEMM (ws too small for bf16 copies): fp32 loads, in-register bf16
// conversion, reg->LDS staging. Writes fp16 X into the slotted layout.
__launch_bounds__(256)
__global__ void gemm_f32stage_kernel(const float* __restrict__ A, const float* __restrict__ Bw,
                                     u16* __restrict__ Xh) {
  __shared__ __align__(16) u16 As[128 * 64];
  __shared__ __align__(16) u16 Bs[128 * 64];
  const int tid  = threadIdx.x;
  const int wave = tid >> 6;
  const int lane = tid & 63;
  const int bm = blockIdx.y, bn = blockIdx.x;
  const int wm = wave >> 1, wn = wave & 1;
  f32x4 acc[4][4] = {};
  const int r0 = tid >> 3;
  const int c8 = (tid & 7) * 8;
  const float* ga = A  + (size_t)(bm * 128 + r0) * D_IN + c8;
  const float* gb = Bw + (size_t)(bn * 128 + r0) * D_IN + c8;

  for (int kt = 0; kt < D_IN / 64; ++kt) {
    u16x8 av[4], bv[4];
#pragma unroll
    for (int i = 0; i < 4; ++i) {
      const float* pa = ga + (size_t)i * 32 * D_IN + kt * 64;
      const float* pb = gb + (size_t)i * 32 * D_IN + kt * 64;
      f32x4 a0 = *(const f32x4*)pa, a1 = *(const f32x4*)(pa + 4);
      f32x4 b0 = *(const f32x4*)pb, b1 = *(const f32x4*)(pb + 4);
#pragma unroll
      for (int q = 0; q < 4; ++q) {
        av[i][q] = f2bf(a0[q]); av[i][q + 4] = f2bf(a1[q]);
        bv[i][q] = f2bf(b0[q]); bv[i][q + 4] = f2bf(b1[q]);
      }
    }
    if (kt) __syncthreads();
#pragma unroll
    for (int i = 0; i < 4; ++i) {
      *(u16x8*)&As[(i * 32 + r0) * 64 + c8] = av[i];
      *(u16x8*)&Bs[(i * 32 + r0) * 64 + c8] = bv[i];
    }
    __syncthreads();
#pragma unroll
    for (int kk = 0; kk < 2; ++kk) {
      const int kc = kk * 32 + ((lane >> 4) << 3);
      bf16x8 af[4], bg[4];
#pragma unroll
      for (int i = 0; i < 4; ++i) {
        af[i] = __builtin_bit_cast(bf16x8, *(const u16x8*)(&As[(wm * 64 + i * 16 + (lane & 15)) * 64 + kc]));
        bg[i] = __builtin_bit_cast(bf16x8, *(const u16x8*)(&Bs[(wn * 64 + i * 16 + (lane & 15)) * 64 + kc]));
      }
#pragma unroll
      for (int i = 0; i < 4; ++i)
#pragma unroll
        for (int j = 0; j < 4; ++j)
          acc[i][j] = __builtin_amdgcn_mfma_f32_16x16x32_bf16(af[i], bg[j], acc[i][j], 0, 0, 0);
    }
  }
#pragma unroll
  for (int i = 0; i < 4; ++i) {
    const int rr = bm * 128 + wm * 64 + i * 16 + ((lane >> 4) << 2);
#pragma unroll
    for (int j = 0; j < 4; ++j) {
      const int c = bn * 128 + wn * 64 + j * 16 + (lane & 15);
#pragma unroll
      for (int r = 0; r < 4; ++r)
        Xh[(size_t)(rr + r) * XSLOT + 2048 + c] = f2h(acc[i][j][r]);
    }
  }
}

// ---------------------------------------------------------------------------
// Kernel 2a: finalize stats from GEMM partials -> fused BN affine.
// scale = istd*gamma, shift = beta - mean*istd*gamma, so
// z = (x*scale + shift)*prior. Reads 8 MB, writes 2 MB.
// ---------------------------------------------------------------------------
__launch_bounds__(256)
__global__ void finalize_stats_kernel(const float* __restrict__ colsum,
                                      const float* __restrict__ colsq,
                                      const float* __restrict__ gamma,
                                      const float* __restrict__ beta,
                                      float* __restrict__ scale, float* __restrict__ shift) {
  const int idx = blockIdx.x * 256 + threadIdx.x;   // vb*D_OUT + c, 262144 total
  const int vb = idx >> 11;
  const int c  = idx & (D_OUT - 1);
  float s = 0.f, q = 0.f;
#pragma unroll
  for (int p = 0; p < 4; ++p) {
    const size_t o = (size_t)(vb * 4 + p) * D_OUT + c;
    s += colsum[o]; q += colsq[o];
  }
  const float m  = s * (1.0f / VBSZ);
  const float is = rsqrtf(q * (1.0f / VBSZ) - m * m + 1e-5f);  // biased var, BN training
  const float sc = is * gamma[c];
  scale[idx] = sc;
  shift[idx] = beta[c] - m * sc;
}

// ---------------------------------------------------------------------------
// Kernel 2b (fallback only): stats from fp16 X -> fused affine.
// ---------------------------------------------------------------------------
__launch_bounds__(256)
__global__ void stats_kernel(const u16* __restrict__ Xh,
                             const float* __restrict__ gamma, const float* __restrict__ beta,
                             float* __restrict__ scale, float* __restrict__ shift) {
  const int vb = blockIdx.y;
  const int c  = blockIdx.x * 256 + threadIdx.x;
  const u16* p = Xh + (size_t)vb * VBSZ * XSLOT + 2048 + c;
  float s = 0.f, q = 0.f;
#pragma unroll 8
  for (int r = 0; r < VBSZ; ++r) {
    const float v = (float)__builtin_bit_cast(_Float16, p[(size_t)r * XSLOT]);
    s += v; q += v * v;
  }
  const float m  = s * (1.0f / VBSZ);
  const float is = rsqrtf(q * (1.0f / VBSZ) - m * m + 1e-5f);
  const size_t o = (size_t)vb * D_OUT + c;
  const float sc = is * gamma[c];
  scale[o] = sc;
  shift[o] = beta[c] - m * sc;
}

// ---------------------------------------------------------------------------
// Kernel 3: BN apply + prior scale + sparsemax. One wave per row; z in 32
// regs; Michelot's algorithm in registers (no LDS). X read as fp16 from the
// upper half of this row's own d_out slot (L3-resident); priors/out use
// nontemporal to avoid evicting X. Block r is the only toucher of slot r,
// and every store depends on tau -> on all X loads, so in-place is safe.
// ---------------------------------------------------------------------------
__launch_bounds__(256)
__global__ void sparsemax_kernel(const u16* Xh, const float* __restrict__ priors,
                                 const float* __restrict__ scale, const float* __restrict__ shift,
                                 float* out) {
  const int wave = threadIdx.x >> 6;
  const int lane = threadIdx.x & 63;
  const int row  = blockIdx.x * 4 + wave;
  const int vb   = row >> 8;
  const size_t rowoff = (size_t)row * D_OUT;
  const u16* xr = Xh + (size_t)row * XSLOT + 2048;

  float z[32];
  float mx = -1e30f;
#pragma unroll
  for (int j = 0; j < 8; ++j) {
    const int c = j * 256 + lane * 4;
    h16x4 xv = __builtin_bit_cast(h16x4, *(const u16x4*)(xr + c));
    f32x4 sc = *(const f32x4*)(scale + (size_t)vb * D_OUT + c);
    f32x4 sh = *(const f32x4*)(shift + (size_t)vb * D_OUT + c);
    f32x4 pr = __builtin_nontemporal_load((const f32x4*)(priors + rowoff + c));
#pragma unroll
    for (int q = 0; q < 4; ++q) {
      const float zz = ((float)xv[q] * sc[q] + sh[q]) * pr[q];
      z[j * 4 + q] = zz;
      mx = fmaxf(mx, zz);
    }
  }
#pragma unroll
  for (int m = 32; m; m >>= 1) mx = fmaxf(mx, __shfl_xor(mx, m, 64));

  // Michelot: f(mx-1) >= 1 => tau* >= mx-1, so S_0 = {z > mx-1} covers the
  // support; tau_t monotonically increases toward tau*, S_t shrinks.
  float thr = mx - 1.0f;
  float kprev = -1.0f;
  float tau;
  for (;;) {
    float s = 0.f, k = 0.f;
#pragma unroll
    for (int j = 0; j < 32; ++j) {
      if (z[j] > thr) { s += z[j]; k += 1.f; }
    }
#pragma unroll
    for (int m = 32; m; m >>= 1) { s += __shfl_xor(s, m, 64); k += __shfl_xor(k, m, 64); }
    tau = (s - 1.0f) / k;
    if (k == kprev) break;   // support stable -> tau exact; wave-uniform
    kprev = k;
    thr = tau;
  }

#pragma unroll
  for (int j = 0; j < 8; ++j) {
    const int c = j * 256 + lane * 4;
    f32x4 o;
#pragma unroll
    for (int q = 0; q < 4; ++q) o[q] = fmaxf(z[j * 4 + q] - tau, 0.f);
    __builtin_nontemporal_store(o, (f32x4*)(out + rowoff + c));
  }
}

// ---------------------------------------------------------------------------
// ws layout (main): [A_bf16 33.5MB][W_bf16 2MB][colsum 4MB][colsq 4MB]
//                   [scale 1MB][shift 1MB] = 45.5 MB.
// Middle path (ws >= 37.5MB): bf16 GEMM without stats epilogue + stats pass.
// Fallback (ws >= 2MB): fp32-staging GEMM + stats pass.
// d_out (fp32, 268MB): X-f16 row r occupies the upper 4KB of out row r's
// 8KB slot — block-local in-place, no cross-block hazard.
// ---------------------------------------------------------------------------
extern "C" void kernel_launch(void* const* d_in, const int* in_sizes, int n_in,
                              void* d_out, int out_size, void* d_ws, size_t ws_size,
                              hipStream_t stream) {
  const float* priors = (const float*)d_in[0];
  const float* feat   = (const float*)d_in[1];
  const float* Wt     = (const float*)d_in[2];
  const float* gamma  = (const float*)d_in[3];
  const float* beta   = (const float*)d_in[4];
  u16*   Xh  = (u16*)d_out;
  float* out = (float*)d_out;

  const size_t a_bytes  = (size_t)B_ROWS * D_IN * sizeof(u16);   // 33.5 MB
  const size_t w_bytes  = (size_t)D_OUT * D_IN * sizeof(u16);    //  2  MB
  const size_t st_elems = (size_t)NVB * D_OUT;                   // 262144
  const size_t pt_elems = (size_t)PROWS * D_OUT;                 // 1048576

  const dim3 ggrid(D_OUT / 128, B_ROWS / 128);
  const int  stats_fin_blocks = (int)(st_elems / 256);           // 1024

  if (ws_size >= a_bytes + w_bytes + (2 * pt_elems + 2 * st_elems) * sizeof(float)) {
    // Main: fused-stats GEMM + fp16 X, no 268 MB stats re-read.
    u16* Ab = (u16*)d_ws;
    u16* Wb = (u16*)((char*)d_ws + a_bytes);
    float* colsum = (float*)((char*)d_ws + a_bytes + w_bytes);
    float* colsq  = colsum + pt_elems;
    float* scale  = colsq + pt_elems;
    float* shift  = scale + st_elems;
    convert_kernel<<<(NA8 + NW8) / 256, 256, 0, stream>>>(feat, Wt, Ab, Wb);
    gemm_bf16_kernel<true><<<ggrid, 256, 0, stream>>>(Ab, Wb, Xh, colsum, colsq);
    finalize_stats_kernel<<<stats_fin_blocks, 256, 0, stream>>>(colsum, colsq, gamma, beta, scale, shift);
    sparsemax_kernel<<<B_ROWS / 4, 256, 0, stream>>>(Xh, priors, scale, shift, out);
  } else if (ws_size >= a_bytes + w_bytes + 2 * st_elems * sizeof(float)) {
    // Middle: bf16 GEMM (no epilogue) + separate stats pass.
    u16* Ab = (u16*)d_ws;
    u16* Wb = (u16*)((char*)d_ws + a_bytes);
    float* scale = (float*)((char*)d_ws + a_bytes + w_bytes);
    float* shift = scale + st_elems;
    convert_kernel<<<(NA8 + NW8) / 256, 256, 0, stream>>>(feat, Wt, Ab, Wb);
    gemm_bf16_kernel<false><<<ggrid, 256, 0, stream>>>(Ab, Wb, Xh, nullptr, nullptr);
    stats_kernel<<<dim3(8, NVB), 256, 0, stream>>>(Xh, gamma, beta, scale, shift);
    sparsemax_kernel<<<B_ROWS / 4, 256, 0, stream>>>(Xh, priors, scale, shift, out);
  } else {
    float* scale = (float*)d_ws;
    float* shift = scale + st_elems;
    gemm_f32stage_kernel<<<ggrid, 256, 0, stream>>>(feat, Wt, Xh);
    stats_kernel<<<dim3(8, NVB), 256, 0, stream>>>(Xh, gamma, beta, scale, shift);
    sparsemax_kernel<<<B_ROWS / 4, 256, 0, stream>>>(Xh, priors, scale, shift, out);
  }
}

// Round 3
// 572.646 us; speedup vs baseline: 1.1645x; 1.0033x over previous
//
#include <hip/hip_runtime.h>
#include <stdint.h>

#define B_ROWS 32768
#define D_IN   512
#define D_OUT  2048
#define VBSZ   256
#define NVB    128   // B_ROWS / VBSZ
#define PROWS  512   // B_ROWS / 64: one partial-stats row per 64-row half-tile
#define XSLOT  4096  // u16 elements per d_out row slot (8 KB); X-f16 row r at slot r, offset +2048

typedef unsigned short u16;
typedef __bf16 bf16x8 __attribute__((ext_vector_type(8)));
typedef float  f32x4  __attribute__((ext_vector_type(4)));
typedef u16    u16x4  __attribute__((ext_vector_type(4)));
typedef u16    u16x8  __attribute__((ext_vector_type(8)));
typedef _Float16 h16x4 __attribute__((ext_vector_type(4)));

__device__ __forceinline__ u16 f2bf(float f) {
  unsigned int u = __builtin_bit_cast(unsigned int, f);
  u += 0x7fffu + ((u >> 16) & 1u);  // RNE; finite inputs
  return (u16)(u >> 16);
}
__device__ __forceinline__ u16 f2h(float f) {
  return __builtin_bit_cast(u16, (_Float16)f);  // v_cvt_f16_f32, RNE
}

// ---------------------------------------------------------------------------
// Kernel 0: fp32 -> bf16 pre-convert of A and W into workspace.
// ---------------------------------------------------------------------------
#define NA8 (B_ROWS * D_IN / 8)   // 2,097,152 groups of 8
#define NW8 (D_OUT * D_IN / 8)    //   131,072 groups of 8
__launch_bounds__(256)
__global__ void convert_kernel(const float* __restrict__ A, const float* __restrict__ W,
                               u16* __restrict__ Ab, u16* __restrict__ Wb) {
  const int idx = blockIdx.x * 256 + threadIdx.x;
  const float* src;
  u16* dst;
  if (idx < NA8)            { src = A + (size_t)idx * 8;         dst = Ab + (size_t)idx * 8; }
  else if (idx < NA8 + NW8) { src = W + (size_t)(idx - NA8) * 8; dst = Wb + (size_t)(idx - NA8) * 8; }
  else return;
  f32x4 a = *(const f32x4*)src, b = *(const f32x4*)(src + 4);
  u16x8 o;
  o[0]=f2bf(a[0]); o[1]=f2bf(a[1]); o[2]=f2bf(a[2]); o[3]=f2bf(a[3]);
  o[4]=f2bf(b[0]); o[5]=f2bf(b[1]); o[6]=f2bf(b[2]); o[7]=f2bf(b[3]);
  *(u16x8*)dst = o;
}

// ---------------------------------------------------------------------------
// Kernel 1: GEMM  X[m][n] = sum_k A[m][k] * W[n][k]  (bf16 in).
// m97 structure: 128x128 tile, BK=64, global_load_lds width-16 staging,
// 16x16x32 bf16 MFMA. X written fp16 into upper 4 KB of d_out 8 KB row slots.
//
// XCD-chunked swizzle (T1, bijective: 4096 % 8 == 0): dispatch-linear id
// orig round-robins XCDs (xcd = orig % 8); give XCD x the contiguous tile
// range [x*512, (x+1)*512) = 32 bm-rows x all 16 bn. Consecutive slots on
// one XCD share the same 131 KB A-tile -> 15/16 of the 536 MB logical A
// re-read becomes XCD-local L2 hits; W (2 MB) stays L2-resident per XCD.
// ---------------------------------------------------------------------------
template <bool DO_STATS>
__launch_bounds__(256)
__global__ void gemm_bf16_kernel(const u16* __restrict__ A, const u16* __restrict__ Bw,
                                 u16* __restrict__ Xh,
                                 float* __restrict__ colsum, float* __restrict__ colsq) {
  __shared__ __align__(16) u16 As[128 * 64];
  __shared__ __align__(16) u16 Bs[128 * 64];
  const int tid  = threadIdx.x;
  const int wave = tid >> 6;
  const int lane = tid & 63;
  const int orig = blockIdx.y * gridDim.x + blockIdx.x;  // dispatch-linear
  const int tile = (orig & 7) * 512 + (orig >> 3);       // XCD-chunked, bijective
  const int bm = tile >> 4, bn = tile & 15;              // bn fastest within chunk
  const int wm = wave >> 1, wn = wave & 1;

  f32x4 acc[4][4] = {};

  // staging: thread t covers tile row (i*32 + t/8), k-cols (t%8)*8 .. +7
  const int r0 = tid >> 3;        // wave*8 + lane/8, 0..31
  const int c8 = (tid & 7) * 8;
  const u16* ga = A  + (size_t)(bm * 128 + r0) * D_IN + c8;
  const u16* gb = Bw + (size_t)(bn * 128 + r0) * D_IN + c8;
  u16* lA = &As[wave * 8 * 64];   // wave-uniform LDS bases
  u16* lB = &Bs[wave * 8 * 64];

  for (int kt = 0; kt < D_IN / 64; ++kt) {
    if (kt) __syncthreads();  // prev tile's LDS reads complete before overwrite
#pragma unroll
    for (int i = 0; i < 4; ++i) {
      __builtin_amdgcn_global_load_lds(
          (const __attribute__((address_space(1))) void*)(ga + (size_t)i * 32 * D_IN + kt * 64),
          (__attribute__((address_space(3))) void*)(lA + i * 32 * 64), 16, 0, 0);
      __builtin_amdgcn_global_load_lds(
          (const __attribute__((address_space(1))) void*)(gb + (size_t)i * 32 * D_IN + kt * 64),
          (__attribute__((address_space(3))) void*)(lB + i * 32 * 64), 16, 0, 0);
    }
    __builtin_amdgcn_s_waitcnt(0x0f70);  // vmcnt(0)
    __syncthreads();

#pragma unroll
    for (int kk = 0; kk < 2; ++kk) {
      const int kc = kk * 32 + ((lane >> 4) << 3);  // frag: k = quad*8 + j
      bf16x8 af[4], bg[4];
#pragma unroll
      for (int i = 0; i < 4; ++i) {
        const int ar = wm * 64 + i * 16 + (lane & 15);
        af[i] = __builtin_bit_cast(bf16x8, *(const u16x8*)(&As[ar * 64 + kc]));
        const int br = wn * 64 + i * 16 + (lane & 15);
        bg[i] = __builtin_bit_cast(bf16x8, *(const u16x8*)(&Bs[br * 64 + kc]));
      }
#pragma unroll
      for (int i = 0; i < 4; ++i)
#pragma unroll
        for (int j = 0; j < 4; ++j)
          acc[i][j] = __builtin_amdgcn_mfma_f32_16x16x32_bf16(af[i], bg[j], acc[i][j], 0, 0, 0);
    }
  }

  // C/D layout: col = lane&15, row = (lane>>4)*4 + reg  [m89/m91]
#pragma unroll
  for (int i = 0; i < 4; ++i) {
    const int rr = bm * 128 + wm * 64 + i * 16 + ((lane >> 4) << 2);
#pragma unroll
    for (int j = 0; j < 4; ++j) {
      const int c = bn * 128 + wn * 64 + j * 16 + (lane & 15);
#pragma unroll
      for (int r = 0; r < 4; ++r)
        Xh[(size_t)(rr + r) * XSLOT + 2048 + c] = f2h(acc[i][j][r]);
    }
  }

  if constexpr (DO_STATS) {
    // This wave's (wm, wn) owns a 64-row x 64-col sub-tile. For column
    // (wn*64 + j*16 + lane&15): thread holds 16 of its 64 rows (i, reg).
    // shfl_xor 16/32 folds lanes {l, l^16, l^32, l^48} (same lane&15) ->
    // full 64-row column sum; lanes 0..15 store the partial.
#pragma unroll
    for (int j = 0; j < 4; ++j) {
      float s = 0.f, q = 0.f;
#pragma unroll
      for (int i = 0; i < 4; ++i)
#pragma unroll
        for (int r = 0; r < 4; ++r) { const float v = acc[i][j][r]; s += v; q += v * v; }
      s += __shfl_xor(s, 16, 64); s += __shfl_xor(s, 32, 64);
      q += __shfl_xor(q, 16, 64); q += __shfl_xor(q, 32, 64);
      if (lane < 16) {
        const int col = bn * 128 + wn * 64 + j * 16 + lane;
        const size_t p = (size_t)(bm * 2 + wm) * D_OUT + col;  // rows bm*128+wm*64 .. +63
        colsum[p] = s;
        colsq[p]  = q;
      }
    }
  }
}

// Fallback GEMM (ws too small for bf16 copies): fp32 loads, in-register bf16
// conversion, reg->LDS staging. Writes fp16 X into the slotted layout.
__launch_bounds__(256)
__global__ void gemm_f32stage_kernel(const float* __restrict__ A, const float* __restrict__ Bw,
                                     u16* __restrict__ Xh) {
  __shared__ __align__(16) u16 As[128 * 64];
  __shared__ __align__(16) u16 Bs[128 * 64];
  const int tid  = threadIdx.x;
  const int wave = tid >> 6;
  const int lane = tid & 63;
  const int orig = blockIdx.y * gridDim.x + blockIdx.x;
  const int tile = (orig & 7) * 512 + (orig >> 3);
  const int bm = tile >> 4, bn = tile & 15;
  const int wm = wave >> 1, wn = wave & 1;
  f32x4 acc[4][4] = {};
  const int r0 = tid >> 3;
  const int c8 = (tid & 7) * 8;
  const float* ga = A  + (size_t)(bm * 128 + r0) * D_IN + c8;
  const float* gb = Bw + (size_t)(bn * 128 + r0) * D_IN + c8;

  for (int kt = 0; kt < D_IN / 64; ++kt) {
    u16x8 av[4], bv[4];
#pragma unroll
    for (int i = 0; i < 4; ++i) {
      const float* pa = ga + (size_t)i * 32 * D_IN + kt * 64;
      const float* pb = gb + (size_t)i * 32 * D_IN + kt * 64;
      f32x4 a0 = *(const f32x4*)pa, a1 = *(const f32x4*)(pa + 4);
      f32x4 b0 = *(const f32x4*)pb, b1 = *(const f32x4*)(pb + 4);
#pragma unroll
      for (int q = 0; q < 4; ++q) {
        av[i][q] = f2bf(a0[q]); av[i][q + 4] = f2bf(a1[q]);
        bv[i][q] = f2bf(b0[q]); bv[i][q + 4] = f2bf(b1[q]);
      }
    }
    if (kt) __syncthreads();
#pragma unroll
    for (int i = 0; i < 4; ++i) {
      *(u16x8*)&As[(i * 32 + r0) * 64 + c8] = av[i];
      *(u16x8*)&Bs[(i * 32 + r0) * 64 + c8] = bv[i];
    }
    __syncthreads();
#pragma unroll
    for (int kk = 0; kk < 2; ++kk) {
      const int kc = kk * 32 + ((lane >> 4) << 3);
      bf16x8 af[4], bg[4];
#pragma unroll
      for (int i = 0; i < 4; ++i) {
        af[i] = __builtin_bit_cast(bf16x8, *(const u16x8*)(&As[(wm * 64 + i * 16 + (lane & 15)) * 64 + kc]));
        bg[i] = __builtin_bit_cast(bf16x8, *(const u16x8*)(&Bs[(wn * 64 + i * 16 + (lane & 15)) * 64 + kc]));
      }
#pragma unroll
      for (int i = 0; i < 4; ++i)
#pragma unroll
        for (int j = 0; j < 4; ++j)
          acc[i][j] = __builtin_amdgcn_mfma_f32_16x16x32_bf16(af[i], bg[j], acc[i][j], 0, 0, 0);
    }
  }
#pragma unroll
  for (int i = 0; i < 4; ++i) {
    const int rr = bm * 128 + wm * 64 + i * 16 + ((lane >> 4) << 2);
#pragma unroll
    for (int j = 0; j < 4; ++j) {
      const int c = bn * 128 + wn * 64 + j * 16 + (lane & 15);
#pragma unroll
      for (int r = 0; r < 4; ++r)
        Xh[(size_t)(rr + r) * XSLOT + 2048 + c] = f2h(acc[i][j][r]);
    }
  }
}

// ---------------------------------------------------------------------------
// Kernel 2a: finalize stats from GEMM partials -> fused BN affine.
// scale = istd*gamma, shift = beta - mean*istd*gamma, so
// z = (x*scale + shift)*prior. Reads 8 MB, writes 2 MB.
// ---------------------------------------------------------------------------
__launch_bounds__(256)
__global__ void finalize_stats_kernel(const float* __restrict__ colsum,
                                      const float* __restrict__ colsq,
                                      const float* __restrict__ gamma,
                                      const float* __restrict__ beta,
                                      float* __restrict__ scale, float* __restrict__ shift) {
  const int idx = blockIdx.x * 256 + threadIdx.x;   // vb*D_OUT + c, 262144 total
  const int vb = idx >> 11;
  const int c  = idx & (D_OUT - 1);
  float s = 0.f, q = 0.f;
#pragma unroll
  for (int p = 0; p < 4; ++p) {
    const size_t o = (size_t)(vb * 4 + p) * D_OUT + c;
    s += colsum[o]; q += colsq[o];
  }
  const float m  = s * (1.0f / VBSZ);
  const float is = rsqrtf(q * (1.0f / VBSZ) - m * m + 1e-5f);  // biased var, BN training
  const float sc = is * gamma[c];
  scale[idx] = sc;
  shift[idx] = beta[c] - m * sc;
}

// ---------------------------------------------------------------------------
// Kernel 2b (fallback only): stats from fp16 X -> fused affine.
// ---------------------------------------------------------------------------
__launch_bounds__(256)
__global__ void stats_kernel(const u16* __restrict__ Xh,
                             const float* __restrict__ gamma, const float* __restrict__ beta,
                             float* __restrict__ scale, float* __restrict__ shift) {
  const int vb = blockIdx.y;
  const int c  = blockIdx.x * 256 + threadIdx.x;
  const u16* p = Xh + (size_t)vb * VBSZ * XSLOT + 2048 + c;
  float s = 0.f, q = 0.f;
#pragma unroll 8
  for (int r = 0; r < VBSZ; ++r) {
    const float v = (float)__builtin_bit_cast(_Float16, p[(size_t)r * XSLOT]);
    s += v; q += v * v;
  }
  const float m  = s * (1.0f / VBSZ);
  const float is = rsqrtf(q * (1.0f / VBSZ) - m * m + 1e-5f);
  const size_t o = (size_t)vb * D_OUT + c;
  const float sc = is * gamma[c];
  scale[o] = sc;
  shift[o] = beta[c] - m * sc;
}

// ---------------------------------------------------------------------------
// Kernel 3: BN apply + prior scale + sparsemax. One wave per row; z in 32
// regs; Michelot's algorithm in registers (no LDS). X read as fp16 from the
// upper half of this row's own d_out slot; priors/out nontemporal.
// XCD swizzle matched to the GEMM's: XCD x handles rows [x*4096,(x+1)*4096)
// — the rows GEMM XCD x wrote — so X re-reads stay on the local L2/L3 path.
// ---------------------------------------------------------------------------
__launch_bounds__(256)
__global__ void sparsemax_kernel(const u16* Xh, const float* __restrict__ priors,
                                 const float* __restrict__ scale, const float* __restrict__ shift,
                                 float* out) {
  const int wave = threadIdx.x >> 6;
  const int lane = threadIdx.x & 63;
  const int b    = blockIdx.x;
  const int bs   = (b & 7) * 1024 + (b >> 3);   // bijective: 8192 % 8 == 0
  const int row  = bs * 4 + wave;
  const int vb   = row >> 8;
  const size_t rowoff = (size_t)row * D_OUT;
  const u16* xr = Xh + (size_t)row * XSLOT + 2048;

  float z[32];
  float mx = -1e30f;
#pragma unroll
  for (int j = 0; j < 8; ++j) {
    const int c = j * 256 + lane * 4;
    h16x4 xv = __builtin_bit_cast(h16x4, *(const u16x4*)(xr + c));
    f32x4 sc = *(const f32x4*)(scale + (size_t)vb * D_OUT + c);
    f32x4 sh = *(const f32x4*)(shift + (size_t)vb * D_OUT + c);
    f32x4 pr = __builtin_nontemporal_load((const f32x4*)(priors + rowoff + c));
#pragma unroll
    for (int q = 0; q < 4; ++q) {
      const float zz = ((float)xv[q] * sc[q] + sh[q]) * pr[q];
      z[j * 4 + q] = zz;
      mx = fmaxf(mx, zz);
    }
  }
#pragma unroll
  for (int m = 32; m; m >>= 1) mx = fmaxf(mx, __shfl_xor(mx, m, 64));

  // Michelot: f(mx-1) >= 1 => tau* >= mx-1, so S_0 = {z > mx-1} covers the
  // support; tau_t monotonically increases toward tau*, S_t shrinks.
  float thr = mx - 1.0f;
  float kprev = -1.0f;
  float tau;
  for (;;) {
    float s = 0.f, k = 0.f;
#pragma unroll
    for (int j = 0; j < 32; ++j) {
      if (z[j] > thr) { s += z[j]; k += 1.f; }
    }
#pragma unroll
    for (int m = 32; m; m >>= 1) { s += __shfl_xor(s, m, 64); k += __shfl_xor(k, m, 64); }
    tau = (s - 1.0f) / k;
    if (k == kprev) break;   // support stable -> tau exact; wave-uniform
    kprev = k;
    thr = tau;
  }

#pragma unroll
  for (int j = 0; j < 8; ++j) {
    const int c = j * 256 + lane * 4;
    f32x4 o;
#pragma unroll
    for (int q = 0; q < 4; ++q) o[q] = fmaxf(z[j * 4 + q] - tau, 0.f);
    __builtin_nontemporal_store(o, (f32x4*)(out + rowoff + c));
  }
}

// ---------------------------------------------------------------------------
// ws layout (main): [A_bf16 33.5MB][W_bf16 2MB][colsum 4MB][colsq 4MB]
//                   [scale 1MB][shift 1MB] = 45.5 MB.
// Middle path (ws >= 37.5MB): bf16 GEMM without stats epilogue + stats pass.
// Fallback (ws >= 2MB): fp32-staging GEMM + stats pass.
// d_out (fp32, 268MB): X-f16 row r occupies the upper 4KB of out row r's
// 8KB slot — block-local in-place, no cross-block hazard.
// ---------------------------------------------------------------------------
extern "C" void kernel_launch(void* const* d_in, const int* in_sizes, int n_in,
                              void* d_out, int out_size, void* d_ws, size_t ws_size,
                              hipStream_t stream) {
  const float* priors = (const float*)d_in[0];
  const float* feat   = (const float*)d_in[1];
  const float* Wt     = (const float*)d_in[2];
  const float* gamma  = (const float*)d_in[3];
  const float* beta   = (const float*)d_in[4];
  u16*   Xh  = (u16*)d_out;
  float* out = (float*)d_out;

  const size_t a_bytes  = (size_t)B_ROWS * D_IN * sizeof(u16);   // 33.5 MB
  const size_t w_bytes  = (size_t)D_OUT * D_IN * sizeof(u16);    //  2  MB
  const size_t st_elems = (size_t)NVB * D_OUT;                   // 262144
  const size_t pt_elems = (size_t)PROWS * D_OUT;                 // 1048576

  const dim3 ggrid(D_OUT / 128, B_ROWS / 128);
  const int  stats_fin_blocks = (int)(st_elems / 256);           // 1024

  if (ws_size >= a_bytes + w_bytes + (2 * pt_elems + 2 * st_elems) * sizeof(float)) {
    // Main: fused-stats GEMM + fp16 X, no 268 MB stats re-read.
    u16* Ab = (u16*)d_ws;
    u16* Wb = (u16*)((char*)d_ws + a_bytes);
    float* colsum = (float*)((char*)d_ws + a_bytes + w_bytes);
    float* colsq  = colsum + pt_elems;
    float* scale  = colsq + pt_elems;
    float* shift  = scale + st_elems;
    convert_kernel<<<(NA8 + NW8) / 256, 256, 0, stream>>>(feat, Wt, Ab, Wb);
    gemm_bf16_kernel<true><<<ggrid, 256, 0, stream>>>(Ab, Wb, Xh, colsum, colsq);
    finalize_stats_kernel<<<stats_fin_blocks, 256, 0, stream>>>(colsum, colsq, gamma, beta, scale, shift);
    sparsemax_kernel<<<B_ROWS / 4, 256, 0, stream>>>(Xh, priors, scale, shift, out);
  } else if (ws_size >= a_bytes + w_bytes + 2 * st_elems * sizeof(float)) {
    // Middle: bf16 GEMM (no epilogue) + separate stats pass.
    u16* Ab = (u16*)d_ws;
    u16* Wb = (u16*)((char*)d_ws + a_bytes);
    float* scale = (float*)((char*)d_ws + a_bytes + w_bytes);
    float* shift = scale + st_elems;
    convert_kernel<<<(NA8 + NW8) / 256, 256, 0, stream>>>(feat, Wt, Ab, Wb);
    gemm_bf16_kernel<false><<<ggrid, 256, 0, stream>>>(Ab, Wb, Xh, nullptr, nullptr);
    stats_kernel<<<dim3(8, NVB), 256, 0, stream>>>(Xh, gamma, beta, scale, shift);
    sparsemax_kernel<<<B_ROWS / 4, 256, 0, stream>>>(Xh, priors, scale, shift, out);
  } else {
    float* scale = (float*)d_ws;
    float* shift = scale + st_elems;
    gemm_f32stage_kernel<<<ggrid, 256, 0, stream>>>(feat, Wt, Xh);
    stats_kernel<<<dim3(8, NVB), 256, 0, stream>>>(Xh, gamma, beta, scale, shift);
    sparsemax_kernel<<<B_ROWS / 4, 256, 0, stream>>>(Xh, priors, scale, shift, out);
  }
}

// Round 4
// 568.098 us; speedup vs baseline: 1.1738x; 1.0080x over previous
//
#include <hip/hip_runtime.h>
#include <stdint.h>

#define B_ROWS 32768
#define D_IN   512
#define D_OUT  2048
#define VBSZ   256
#define NVB    128   // B_ROWS / VBSZ
#define PROWS  512   // B_ROWS / 64: one partial-stats row per 64-row group
#define XSLOT  4096  // u16 per d_out row slot (8 KB); X-f16 row r at +2048

typedef unsigned short u16;
typedef __bf16 bf16x8 __attribute__((ext_vector_type(8)));
typedef float  f32x4  __attribute__((ext_vector_type(4)));
typedef u16    u16x4  __attribute__((ext_vector_type(4)));
typedef u16    u16x8  __attribute__((ext_vector_type(8)));
typedef _Float16 h16x4 __attribute__((ext_vector_type(4)));

__device__ __forceinline__ u16 f2bf(float f) {
  unsigned int u = __builtin_bit_cast(unsigned int, f);
  u += 0x7fffu + ((u >> 16) & 1u);  // RNE; finite inputs
  return (u16)(u >> 16);
}
__device__ __forceinline__ u16 f2h(float f) {
  return __builtin_bit_cast(u16, (_Float16)f);  // v_cvt_f16_f32, RNE
}

// ---------------------------------------------------------------------------
// Kernel 0: fp32 -> bf16 pre-convert of A and W into workspace.
// ---------------------------------------------------------------------------
#define NA8 (B_ROWS * D_IN / 8)
#define NW8 (D_OUT * D_IN / 8)
__launch_bounds__(256)
__global__ void convert_kernel(const float* __restrict__ A, const float* __restrict__ W,
                               u16* __restrict__ Ab, u16* __restrict__ Wb) {
  const int idx = blockIdx.x * 256 + threadIdx.x;
  const float* src;
  u16* dst;
  if (idx < NA8)            { src = A + (size_t)idx * 8;         dst = Ab + (size_t)idx * 8; }
  else if (idx < NA8 + NW8) { src = W + (size_t)(idx - NA8) * 8; dst = Wb + (size_t)(idx - NA8) * 8; }
  else return;
  f32x4 a = *(const f32x4*)src, b = *(const f32x4*)(src + 4);
  u16x8 o;
  o[0]=f2bf(a[0]); o[1]=f2bf(a[1]); o[2]=f2bf(a[2]); o[3]=f2bf(a[3]);
  o[4]=f2bf(b[0]); o[5]=f2bf(b[1]); o[6]=f2bf(b[2]); o[7]=f2bf(b[3]);
  *(u16x8*)dst = o;
}

// ---------------------------------------------------------------------------
// Kernel 1 (main): 256x256-tile 8-phase GEMM, X[m][n] = sum_k A[m][k]*W[n][k].
// 512 thr = 8 waves (2M x 4N), per-wave C = 128x64. BK=64, 8 K-tiles, 2/iter.
// LDS 128 KiB: As/Bs[2 buf][256][64] bf16, 16B-slot XOR-swizzle (slot ^= row&7)
// applied via inverse-swizzled GLOBAL source (gload_lds dest linear) and
// swizzled ds_read (rule 21). Raw s_barrier only; counted vmcnt(6) at phases
// 3/7 keeps 3 half-tiles (6 loads) in flight across barriers (T3+T4);
// setprio around MFMA clusters (T5).
// Stage calendar (iter it reads K-tiles 2it/buf0 ph0-3, 2it+1/buf1 ph4-7):
//   ph0: K(2it+1).A1   ph1: K(2it+2).B0  ph2: K(2it+2).B1  ph3: K(2it+2).A0
//   ph4: K(2it+2).A1   ph5: K(2it+3).B0  ph6: K(2it+3).B1  ph7: K(2it+3).A0
// Windows verified: every stage targets a region whose last ds_read finished
// >=1 barrier earlier; vmcnt(6) at ph3/ph7 guarantees exactly the next
// K-tile's 4 halves landed. Prologue stages 7 halves (K0 full + K1 B0,B1,A0).
// A-quarter ds_reads run one phase ahead (afE/afO) so A regions free at ph+2.
// Epilogue: fp16 X into d_out row slots + per-wave column sum/sumsq partials.
// ---------------------------------------------------------------------------
__launch_bounds__(512, 2)
__global__ void gemm256_kernel(const u16* __restrict__ A, const u16* __restrict__ Bw,
                               u16* __restrict__ Xh,
                               float* __restrict__ colsum, float* __restrict__ colsq) {
  __shared__ __align__(16) u16 As[2 * 256 * 64];
  __shared__ __align__(16) u16 Bs[2 * 256 * 64];
  const int tid  = threadIdx.x;
  const int wave = tid >> 6;
  const int lane = tid & 63;
  const int orig = blockIdx.y * gridDim.x + blockIdx.x;   // 0..1023
  const int tile = (orig & 7) * 128 + (orig >> 3);        // XCD-chunked, bijective
  const int bm = tile >> 3, bn = tile & 7;
  const int wm = wave >> 2, wn = wave & 3;

  // staging addressing: thread t covers row (t>>3) within a 64-row round,
  // 16B slot (t&7); global k pre-swizzled so LDS stays linear (m173 pattern).
  const int kswz = (((tid & 7) ^ ((tid >> 3) & 7)) << 3);
  const u16* ga0 = A  + (size_t)(bm * 256 + (tid >> 3)) * D_IN + kswz;
  const u16* gb0 = Bw + (size_t)(bn * 256 + (tid >> 3)) * D_IN + kswz;
  u16* lA0 = As + wave * 512;   // + CB*16384 + (H*128 + rho*64)*64 per call
  u16* lB0 = Bs + wave * 512;

#define STAGE_A(CB, H, KT) do {                                                          \
    __builtin_amdgcn_global_load_lds(                                                    \
        (const __attribute__((address_space(1))) void*)(ga0 + (size_t)((H)*128) * D_IN + (KT)*64), \
        (__attribute__((address_space(3))) void*)(lA0 + (CB)*16384 + ((H)*128)*64), 16, 0, 0);     \
    __builtin_amdgcn_global_load_lds(                                                    \
        (const __attribute__((address_space(1))) void*)(ga0 + (size_t)((H)*128+64) * D_IN + (KT)*64), \
        (__attribute__((address_space(3))) void*)(lA0 + (CB)*16384 + ((H)*128+64)*64), 16, 0, 0);  \
  } while (0)
#define STAGE_B(CB, H, KT) do {                                                          \
    __builtin_amdgcn_global_load_lds(                                                    \
        (const __attribute__((address_space(1))) void*)(gb0 + (size_t)((H)*128) * D_IN + (KT)*64), \
        (__attribute__((address_space(3))) void*)(lB0 + (CB)*16384 + ((H)*128)*64), 16, 0, 0);     \
    __builtin_amdgcn_global_load_lds(                                                    \
        (const __attribute__((address_space(1))) void*)(gb0 + (size_t)((H)*128+64) * D_IN + (KT)*64), \
        (__attribute__((address_space(3))) void*)(lB0 + (CB)*16384 + ((H)*128+64)*64), 16, 0, 0);  \
  } while (0)

  // fragment read addressing (swizzled): row&7 == lane&7 for all frag rows
  const int arow  = (wm * 128 + (lane & 15)) * 64;
  const int brow  = (wn * 64  + (lane & 15)) * 64;
  const int aswz0 = (((lane >> 4)    ) ^ (lane & 7)) << 3;   // kk=0
  const int aswz1 = (((lane >> 4) + 4) ^ (lane & 7)) << 3;   // kk=1

#define LDA(CB, Q, DST) do {                                                                   \
    DST[0] = __builtin_bit_cast(bf16x8, *(const u16x8*)(&As[(CB)*16384 + arow + ((Q)*2+0)*1024 + aswz0])); \
    DST[1] = __builtin_bit_cast(bf16x8, *(const u16x8*)(&As[(CB)*16384 + arow + ((Q)*2+0)*1024 + aswz1])); \
    DST[2] = __builtin_bit_cast(bf16x8, *(const u16x8*)(&As[(CB)*16384 + arow + ((Q)*2+1)*1024 + aswz0])); \
    DST[3] = __builtin_bit_cast(bf16x8, *(const u16x8*)(&As[(CB)*16384 + arow + ((Q)*2+1)*1024 + aswz1])); \
  } while (0)
#define LDB(CB) do {                                                                           \
    _Pragma("unroll") for (int j = 0; j < 4; ++j) {                                            \
      bq[j][0] = __builtin_bit_cast(bf16x8, *(const u16x8*)(&Bs[(CB)*16384 + brow + j*1024 + aswz0])); \
      bq[j][1] = __builtin_bit_cast(bf16x8, *(const u16x8*)(&Bs[(CB)*16384 + brow + j*1024 + aswz1])); \
    }                                                                                          \
  } while (0)
#define MFMA16(Q, AF) do {                                                                     \
    __builtin_amdgcn_s_setprio(1);                                                             \
    _Pragma("unroll") for (int j = 0; j < 4; ++j) {                                            \
      acc[(Q)*2+0][j] = __builtin_amdgcn_mfma_f32_16x16x32_bf16(AF[0], bq[j][0], acc[(Q)*2+0][j], 0, 0, 0); \
      acc[(Q)*2+0][j] = __builtin_amdgcn_mfma_f32_16x16x32_bf16(AF[1], bq[j][1], acc[(Q)*2+0][j], 0, 0, 0); \
      acc[(Q)*2+1][j] = __builtin_amdgcn_mfma_f32_16x16x32_bf16(AF[2], bq[j][0], acc[(Q)*2+1][j], 0, 0, 0); \
      acc[(Q)*2+1][j] = __builtin_amdgcn_mfma_f32_16x16x32_bf16(AF[3], bq[j][1], acc[(Q)*2+1][j], 0, 0, 0); \
    }                                                                                          \
    __builtin_amdgcn_s_setprio(0);                                                             \
  } while (0)
#define BAR() __builtin_amdgcn_s_barrier()
#define WVM(N) __builtin_amdgcn_s_waitcnt(0x0f70 | (N))   // vmcnt(N), lgkm/exp free

  f32x4  acc[8][4] = {};
  bf16x8 bq[4][2];
  bf16x8 afE[4], afO[4];

  // ---- prologue: 7 half-tiles (K0 full, K1 B0/B1/A0); vmcnt(6) -> K0 landed
  STAGE_B(0, 0, 0); STAGE_B(0, 1, 0); STAGE_A(0, 0, 0); STAGE_A(0, 1, 0);
  STAGE_B(1, 0, 1); STAGE_B(1, 1, 1); STAGE_A(1, 0, 1);
  WVM(6);
  BAR();

  for (int it = 0; it < 4; ++it) {
    const bool more = (it < 3);
    // ---- phase 0: K-tile 2it (buf0). Read B + A-q0,q1; stage K(2it+1).A1.
    LDB(0); LDA(0, 0, afE); LDA(0, 1, afO);
    STAGE_A(1, 1, 2 * it + 1);
    BAR();
    MFMA16(0, afE);
    BAR();
    // ---- phase 1: read A-q2; stage K(2it+2).B0 (buf0.B free since ph0).
    LDA(0, 2, afE);
    if (more) STAGE_B(0, 0, 2 * it + 2);
    BAR();
    MFMA16(1, afO);
    BAR();
    // ---- phase 2: read A-q3; stage K(2it+2).B1.
    LDA(0, 3, afO);
    if (more) STAGE_B(0, 1, 2 * it + 2);
    BAR();
    MFMA16(2, afE);
    BAR();
    // ---- phase 3: stage K(2it+2).A0 (buf0.A free since ph2); CHECKPOINT.
    if (more) STAGE_A(0, 0, 2 * it + 2);
    if (more) WVM(6); else WVM(0);   // guarantees K(2it+1) fully landed
    BAR();
    MFMA16(3, afO);
    BAR();
    // ---- phase 4: K-tile 2it+1 (buf1). Read B + A-q0,q1; stage K(2it+2).A1.
    LDB(1); LDA(1, 0, afE); LDA(1, 1, afO);
    if (more) STAGE_A(0, 1, 2 * it + 2);
    BAR();
    MFMA16(0, afE);
    BAR();
    // ---- phase 5: read A-q2; stage K(2it+3).B0 (buf1.B free since ph4).
    LDA(1, 2, afE);
    if (more) STAGE_B(1, 0, 2 * it + 3);
    BAR();
    MFMA16(1, afO);
    BAR();
    // ---- phase 6: read A-q3; stage K(2it+3).B1.
    LDA(1, 3, afO);
    if (more) STAGE_B(1, 1, 2 * it + 3);
    BAR();
    MFMA16(2, afE);
    BAR();
    // ---- phase 7: stage K(2it+3).A0 (buf1.A free since ph6); CHECKPOINT.
    if (more) { STAGE_A(1, 0, 2 * it + 3); WVM(6); }  // K(2it+2) landed
    BAR();
    MFMA16(3, afO);
    BAR();
  }

  // ---- epilogue: fp16 X into d_out slots (C/D: col=lane&15, row=(lane>>4)*4+r)
#pragma unroll
  for (int i = 0; i < 8; ++i) {
    const int rr = bm * 256 + wm * 128 + i * 16 + ((lane >> 4) << 2);
#pragma unroll
    for (int j = 0; j < 4; ++j) {
      const int c = bn * 256 + wn * 64 + j * 16 + (lane & 15);
#pragma unroll
      for (int r = 0; r < 4; ++r)
        Xh[(size_t)(rr + r) * XSLOT + 2048 + c] = f2h(acc[i][j][r]);
    }
  }
  // ---- stats partials: per 64-row group g = i>>2 of this wave's 128 rows.
#pragma unroll
  for (int g = 0; g < 2; ++g) {
#pragma unroll
    for (int j = 0; j < 4; ++j) {
      float s = 0.f, q = 0.f;
#pragma unroll
      for (int ii = 0; ii < 4; ++ii)
#pragma unroll
        for (int r = 0; r < 4; ++r) { const float v = acc[g * 4 + ii][j][r]; s += v; q += v * v; }
      s += __shfl_xor(s, 16, 64); s += __shfl_xor(s, 32, 64);
      q += __shfl_xor(q, 16, 64); q += __shfl_xor(q, 32, 64);
      if (lane < 16) {
        const int col = bn * 256 + wn * 64 + j * 16 + lane;
        const size_t p = (size_t)(bm * 4 + wm * 2 + g) * D_OUT + col;  // rows .. 64-group
        colsum[p] = s;
        colsq[p]  = q;
      }
    }
  }
#undef STAGE_A
#undef STAGE_B
#undef LDA
#undef LDB
#undef MFMA16
#undef BAR
#undef WVM
}

// ---------------------------------------------------------------------------
// Kernel 1b (middle path): verified 128x128 m97-structure GEMM (no stats).
// ---------------------------------------------------------------------------
__launch_bounds__(256)
__global__ void gemm_bf16_kernel(const u16* __restrict__ A, const u16* __restrict__ Bw,
                                 u16* __restrict__ Xh) {
  __shared__ __align__(16) u16 As[128 * 64];
  __shared__ __align__(16) u16 Bs[128 * 64];
  const int tid  = threadIdx.x;
  const int wave = tid >> 6;
  const int lane = tid & 63;
  const int bm = blockIdx.y, bn = blockIdx.x;
  const int wm = wave >> 1, wn = wave & 1;
  f32x4 acc[4][4] = {};
  const int r0 = tid >> 3;
  const int c8 = (tid & 7) * 8;
  const u16* ga = A  + (size_t)(bm * 128 + r0) * D_IN + c8;
  const u16* gb = Bw + (size_t)(bn * 128 + r0) * D_IN + c8;
  u16* lA = &As[wave * 8 * 64];
  u16* lB = &Bs[wave * 8 * 64];
  for (int kt = 0; kt < D_IN / 64; ++kt) {
    if (kt) __syncthreads();
#pragma unroll
    for (int i = 0; i < 4; ++i) {
      __builtin_amdgcn_global_load_lds(
          (const __attribute__((address_space(1))) void*)(ga + (size_t)i * 32 * D_IN + kt * 64),
          (__attribute__((address_space(3))) void*)(lA + i * 32 * 64), 16, 0, 0);
      __builtin_amdgcn_global_load_lds(
          (const __attribute__((address_space(1))) void*)(gb + (size_t)i * 32 * D_IN + kt * 64),
          (__attribute__((address_space(3))) void*)(lB + i * 32 * 64), 16, 0, 0);
    }
    __builtin_amdgcn_s_waitcnt(0x0f70);
    __syncthreads();
#pragma unroll
    for (int kk = 0; kk < 2; ++kk) {
      const int kc = kk * 32 + ((lane >> 4) << 3);
      bf16x8 af[4], bg[4];
#pragma unroll
      for (int i = 0; i < 4; ++i) {
        af[i] = __builtin_bit_cast(bf16x8, *(const u16x8*)(&As[(wm * 64 + i * 16 + (lane & 15)) * 64 + kc]));
        bg[i] = __builtin_bit_cast(bf16x8, *(const u16x8*)(&Bs[(wn * 64 + i * 16 + (lane & 15)) * 64 + kc]));
      }
#pragma unroll
      for (int i = 0; i < 4; ++i)
#pragma unroll
        for (int j = 0; j < 4; ++j)
          acc[i][j] = __builtin_amdgcn_mfma_f32_16x16x32_bf16(af[i], bg[j], acc[i][j], 0, 0, 0);
    }
  }
#pragma unroll
  for (int i = 0; i < 4; ++i) {
    const int rr = bm * 128 + wm * 64 + i * 16 + ((lane >> 4) << 2);
#pragma unroll
    for (int j = 0; j < 4; ++j) {
      const int c = bn * 128 + wn * 64 + j * 16 + (lane & 15);
#pragma unroll
      for (int r = 0; r < 4; ++r)
        Xh[(size_t)(rr + r) * XSLOT + 2048 + c] = f2h(acc[i][j][r]);
    }
  }
}

// Fallback GEMM (tiny ws): fp32 loads, in-register bf16 convert, reg->LDS.
__launch_bounds__(256)
__global__ void gemm_f32stage_kernel(const float* __restrict__ A, const float* __restrict__ Bw,
                                     u16* __restrict__ Xh) {
  __shared__ __align__(16) u16 As[128 * 64];
  __shared__ __align__(16) u16 Bs[128 * 64];
  const int tid  = threadIdx.x;
  const int wave = tid >> 6;
  const int lane = tid & 63;
  const int bm = blockIdx.y, bn = blockIdx.x;
  const int wm = wave >> 1, wn = wave & 1;
  f32x4 acc[4][4] = {};
  const int r0 = tid >> 3;
  const int c8 = (tid & 7) * 8;
  const float* ga = A  + (size_t)(bm * 128 + r0) * D_IN + c8;
  const float* gb = Bw + (size_t)(bn * 128 + r0) * D_IN + c8;
  for (int kt = 0; kt < D_IN / 64; ++kt) {
    u16x8 av[4], bv[4];
#pragma unroll
    for (int i = 0; i < 4; ++i) {
      const float* pa = ga + (size_t)i * 32 * D_IN + kt * 64;
      const float* pb = gb + (size_t)i * 32 * D_IN + kt * 64;
      f32x4 a0 = *(const f32x4*)pa, a1 = *(const f32x4*)(pa + 4);
      f32x4 b0 = *(const f32x4*)pb, b1 = *(const f32x4*)(pb + 4);
#pragma unroll
      for (int q = 0; q < 4; ++q) {
        av[i][q] = f2bf(a0[q]); av[i][q + 4] = f2bf(a1[q]);
        bv[i][q] = f2bf(b0[q]); bv[i][q + 4] = f2bf(b1[q]);
      }
    }
    if (kt) __syncthreads();
#pragma unroll
    for (int i = 0; i < 4; ++i) {
      *(u16x8*)&As[(i * 32 + r0) * 64 + c8] = av[i];
      *(u16x8*)&Bs[(i * 32 + r0) * 64 + c8] = bv[i];
    }
    __syncthreads();
#pragma unroll
    for (int kk = 0; kk < 2; ++kk) {
      const int kc = kk * 32 + ((lane >> 4) << 3);
      bf16x8 af[4], bg[4];
#pragma unroll
      for (int i = 0; i < 4; ++i) {
        af[i] = __builtin_bit_cast(bf16x8, *(const u16x8*)(&As[(wm * 64 + i * 16 + (lane & 15)) * 64 + kc]));
        bg[i] = __builtin_bit_cast(bf16x8, *(const u16x8*)(&Bs[(wn * 64 + i * 16 + (lane & 15)) * 64 + kc]));
      }
#pragma unroll
      for (int i = 0; i < 4; ++i)
#pragma unroll
        for (int j = 0; j < 4; ++j)
          acc[i][j] = __builtin_amdgcn_mfma_f32_16x16x32_bf16(af[i], bg[j], acc[i][j], 0, 0, 0);
    }
  }
#pragma unroll
  for (int i = 0; i < 4; ++i) {
    const int rr = bm * 128 + wm * 64 + i * 16 + ((lane >> 4) << 2);
#pragma unroll
    for (int j = 0; j < 4; ++j) {
      const int c = bn * 128 + wn * 64 + j * 16 + (lane & 15);
#pragma unroll
      for (int r = 0; r < 4; ++r)
        Xh[(size_t)(rr + r) * XSLOT + 2048 + c] = f2h(acc[i][j][r]);
    }
  }
}

// ---------------------------------------------------------------------------
// Kernel 2a: finalize stats from GEMM partials -> fused BN affine.
// ---------------------------------------------------------------------------
__launch_bounds__(256)
__global__ void finalize_stats_kernel(const float* __restrict__ colsum,
                                      const float* __restrict__ colsq,
                                      const float* __restrict__ gamma,
                                      const float* __restrict__ beta,
                                      float* __restrict__ scale, float* __restrict__ shift) {
  const int idx = blockIdx.x * 256 + threadIdx.x;
  const int vb = idx >> 11;
  const int c  = idx & (D_OUT - 1);
  float s = 0.f, q = 0.f;
#pragma unroll
  for (int p = 0; p < 4; ++p) {
    const size_t o = (size_t)(vb * 4 + p) * D_OUT + c;
    s += colsum[o]; q += colsq[o];
  }
  const float m  = s * (1.0f / VBSZ);
  const float is = rsqrtf(q * (1.0f / VBSZ) - m * m + 1e-5f);
  const float sc = is * gamma[c];
  scale[idx] = sc;
  shift[idx] = beta[c] - m * sc;
}

// ---------------------------------------------------------------------------
// Kernel 2b (fallback paths): stats from fp16 X -> fused affine.
// ---------------------------------------------------------------------------
__launch_bounds__(256)
__global__ void stats_kernel(const u16* __restrict__ Xh,
                             const float* __restrict__ gamma, const float* __restrict__ beta,
                             float* __restrict__ scale, float* __restrict__ shift) {
  const int vb = blockIdx.y;
  const int c  = blockIdx.x * 256 + threadIdx.x;
  const u16* p = Xh + (size_t)vb * VBSZ * XSLOT + 2048 + c;
  float s = 0.f, q = 0.f;
#pragma unroll 8
  for (int r = 0; r < VBSZ; ++r) {
    const float v = (float)__builtin_bit_cast(_Float16, p[(size_t)r * XSLOT]);
    s += v; q += v * v;
  }
  const float m  = s * (1.0f / VBSZ);
  const float is = rsqrtf(q * (1.0f / VBSZ) - m * m + 1e-5f);
  const size_t o = (size_t)vb * D_OUT + c;
  const float sc = is * gamma[c];
  scale[o] = sc;
  shift[o] = beta[c] - m * sc;
}

// ---------------------------------------------------------------------------
// Kernel 3: BN apply + prior scale + sparsemax (Michelot in registers).
// ---------------------------------------------------------------------------
__launch_bounds__(256)
__global__ void sparsemax_kernel(const u16* Xh, const float* __restrict__ priors,
                                 const float* __restrict__ scale, const float* __restrict__ shift,
                                 float* out) {
  const int wave = threadIdx.x >> 6;
  const int lane = threadIdx.x & 63;
  const int b    = blockIdx.x;
  const int bs   = (b & 7) * 1024 + (b >> 3);   // bijective: 8192 % 8 == 0
  const int row  = bs * 4 + wave;
  const int vb   = row >> 8;
  const size_t rowoff = (size_t)row * D_OUT;
  const u16* xr = Xh + (size_t)row * XSLOT + 2048;

  float z[32];
  float mx = -1e30f;
#pragma unroll
  for (int j = 0; j < 8; ++j) {
    const int c = j * 256 + lane * 4;
    h16x4 xv = __builtin_bit_cast(h16x4, *(const u16x4*)(xr + c));
    f32x4 sc = *(const f32x4*)(scale + (size_t)vb * D_OUT + c);
    f32x4 sh = *(const f32x4*)(shift + (size_t)vb * D_OUT + c);
    f32x4 pr = __builtin_nontemporal_load((const f32x4*)(priors + rowoff + c));
#pragma unroll
    for (int q = 0; q < 4; ++q) {
      const float zz = ((float)xv[q] * sc[q] + sh[q]) * pr[q];
      z[j * 4 + q] = zz;
      mx = fmaxf(mx, zz);
    }
  }
#pragma unroll
  for (int m = 32; m; m >>= 1) mx = fmaxf(mx, __shfl_xor(mx, m, 64));

  float thr = mx - 1.0f;
  float kprev = -1.0f;
  float tau;
  for (;;) {
    float s = 0.f, k = 0.f;
#pragma unroll
    for (int j = 0; j < 32; ++j) {
      if (z[j] > thr) { s += z[j]; k += 1.f; }
    }
#pragma unroll
    for (int m = 32; m; m >>= 1) { s += __shfl_xor(s, m, 64); k += __shfl_xor(k, m, 64); }
    tau = (s - 1.0f) / k;
    if (k == kprev) break;
    kprev = k;
    thr = tau;
  }

#pragma unroll
  for (int j = 0; j < 8; ++j) {
    const int c = j * 256 + lane * 4;
    f32x4 o;
#pragma unroll
    for (int q = 0; q < 4; ++q) o[q] = fmaxf(z[j * 4 + q] - tau, 0.f);
    __builtin_nontemporal_store(o, (f32x4*)(out + rowoff + c));
  }
}

// ---------------------------------------------------------------------------
// ws layout (main): [A_bf16 33.5MB][W_bf16 2MB][colsum 4MB][colsq 4MB]
//                   [scale 1MB][shift 1MB] = 45.5 MB.
// ---------------------------------------------------------------------------
extern "C" void kernel_launch(void* const* d_in, const int* in_sizes, int n_in,
                              void* d_out, int out_size, void* d_ws, size_t ws_size,
                              hipStream_t stream) {
  const float* priors = (const float*)d_in[0];
  const float* feat   = (const float*)d_in[1];
  const float* Wt     = (const float*)d_in[2];
  const float* gamma  = (const float*)d_in[3];
  const float* beta   = (const float*)d_in[4];
  u16*   Xh  = (u16*)d_out;
  float* out = (float*)d_out;

  const size_t a_bytes  = (size_t)B_ROWS * D_IN * sizeof(u16);
  const size_t w_bytes  = (size_t)D_OUT * D_IN * sizeof(u16);
  const size_t st_elems = (size_t)NVB * D_OUT;
  const size_t pt_elems = (size_t)PROWS * D_OUT;
  const int    stats_fin_blocks = (int)(st_elems / 256);

  if (ws_size >= a_bytes + w_bytes + (2 * pt_elems + 2 * st_elems) * sizeof(float)) {
    // Main: 256^2 8-phase fused-stats GEMM.
    u16* Ab = (u16*)d_ws;
    u16* Wb = (u16*)((char*)d_ws + a_bytes);
    float* colsum = (float*)((char*)d_ws + a_bytes + w_bytes);
    float* colsq  = colsum + pt_elems;
    float* scale  = colsq + pt_elems;
    float* shift  = scale + st_elems;
    convert_kernel<<<(NA8 + NW8) / 256, 256, 0, stream>>>(feat, Wt, Ab, Wb);
    gemm256_kernel<<<dim3(D_OUT / 256, B_ROWS / 256), 512, 0, stream>>>(Ab, Wb, Xh, colsum, colsq);
    finalize_stats_kernel<<<stats_fin_blocks, 256, 0, stream>>>(colsum, colsq, gamma, beta, scale, shift);
    sparsemax_kernel<<<B_ROWS / 4, 256, 0, stream>>>(Xh, priors, scale, shift, out);
  } else if (ws_size >= a_bytes + w_bytes + 2 * st_elems * sizeof(float)) {
    // Middle: 128^2 bf16 GEMM + separate stats pass.
    u16* Ab = (u16*)d_ws;
    u16* Wb = (u16*)((char*)d_ws + a_bytes);
    float* scale = (float*)((char*)d_ws + a_bytes + w_bytes);
    float* shift = scale + st_elems;
    convert_kernel<<<(NA8 + NW8) / 256, 256, 0, stream>>>(feat, Wt, Ab, Wb);
    gemm_bf16_kernel<<<dim3(D_OUT / 128, B_ROWS / 128), 256, 0, stream>>>(Ab, Wb, Xh);
    stats_kernel<<<dim3(8, NVB), 256, 0, stream>>>(Xh, gamma, beta, scale, shift);
    sparsemax_kernel<<<B_ROWS / 4, 256, 0, stream>>>(Xh, priors, scale, shift, out);
  } else {
    float* scale = (float*)d_ws;
    float* shift = scale + st_elems;
    gemm_f32stage_kernel<<<dim3(D_OUT / 128, B_ROWS / 128), 256, 0, stream>>>(feat, Wt, Xh);
    stats_kernel<<<dim3(8, NVB), 256, 0, stream>>>(Xh, gamma, beta, scale, shift);
    sparsemax_kernel<<<B_ROWS / 4, 256, 0, stream>>>(Xh, priors, scale, shift, out);
  }
}